// Round 5
// baseline (503.469 us; speedup 1.0000x reference)
//
#include <hip/hip_runtime.h>

#define T_STEPS 512
#define BT 16          // batches per block (one 16-row MFMA tile)
#define XSTRIDE 520    // padded x row stride (floats), %4==0 for float4 alignment
#define HSTRIDE 72     // padded h row stride (shorts): 144B rows -> every bf16x8 read 16B-aligned
#define E2S 65         // exch row stride in float2: 64 columns + 1 pad (unique slot per (b,k))

typedef __attribute__((ext_vector_type(8))) short bf16x8;
typedef __attribute__((ext_vector_type(4))) float f32x4;

#if __has_builtin(__builtin_amdgcn_exp2f)
#define EXP2F(x) __builtin_amdgcn_exp2f(x)
#else
#define EXP2F(x) exp2f(x)
#endif
#define RCPF(x) __builtin_amdgcn_rcpf(x)

__device__ __forceinline__ short f2bf(float f) {
    union { float f; unsigned u; } v; v.f = f;
    unsigned r = v.u + 0x7fffu + ((v.u >> 16) & 1u);   // RNE
    return (short)(r >> 16);
}
__device__ __forceinline__ float bf2f(short s) {
    union { float f; unsigned u; } v;
    v.u = ((unsigned)(unsigned short)s) << 16;
    return v.f;
}

// LOG2E scaling folded into weights/bias:
//   i,f,o rows scaled by -log2e  -> sig(z)  = rcp(1 + exp2(acc))
//   g rows scaled by +2*log2e    -> tanh(z) = 1 - 2*rcp(1 + exp2(acc))
#define NLOG2E  (-1.4426950408889634f)
#define P2LOG2E ( 2.8853900817779268f)

__global__ __launch_bounds__(512) void lstm_persist(
    const float* __restrict__ x,      // [B, T]
    const float* __restrict__ W_ih,   // [256]
    const float* __restrict__ W_hh,   // [256,64]
    const float* __restrict__ b_ih,   // [256]
    const float* __restrict__ b_hh,   // [256]
    const float* __restrict__ W_fc,   // [64]
    const float* __restrict__ b_fc,   // [1]
    float* __restrict__ out)          // [B]
{
    __shared__ __align__(16) float  x_lds[BT * XSTRIDE];        // 33.3 KB
    __shared__ __align__(16) short  hbuf[2][2][BT][HSTRIDE];    // 9.2 KB [buf][hi/lo][b][k]
    __shared__ __align__(8)  float2 exch[BT * E2S];             // 8.3 KB gate exchange

    const int tid  = threadIdx.x;
    const int wave = tid >> 6;     // 0..7
    const int lane = tid & 63;
    const int l15  = lane & 15;
    const int quad = lane >> 4;    // 0..3
    const int s    = wave & 3;     // column slice: k in [16s, 16s+16)
    const int p    = wave >> 2;    // 0 -> gates (i,f); 1 -> gates (g,o)
    const int b0   = blockIdx.x * BT;

    // ---- stage x[b0..b0+15][0..511] into LDS (coalesced float4) ----
    {
        const float* xg = x + (size_t)b0 * T_STEPS;
        #pragma unroll
        for (int i = 0; i < 4; ++i) {
            int f4 = tid + i * 512;        // 0..2047
            int b  = f4 >> 7;              // 128 float4 per row
            int t4 = f4 & 127;
            float4 v = reinterpret_cast<const float4*>(xg + (size_t)b * T_STEPS)[t4];
            reinterpret_cast<float4*>(&x_lds[b * XSTRIDE + t4 * 4])[0] = v;
        }
    }
    // ---- zero h buffer 0 (hi + lo) ----
    for (int i = tid; i < 2 * BT * HSTRIDE; i += 512) (&hbuf[0][0][0][0])[i] = 0;

    // ---- resident W_hh fragments (2 gates, exp2-scaled, hi/lo split), bias, W_ih ----
    // B-frag: lane holds B[k = quad*8+j (+32*kh)][n = l15]
    bf16x8 Bhi[2][2], Blo[2][2];
    float bias_s[2], wih_s[2];
    const int kcol = s * 16 + l15;
    #pragma unroll
    for (int j = 0; j < 2; ++j) {
        int tgt = 2 * p + j;                       // 0=i 1=f 2=g 3=o
        float sc = (tgt == 2) ? P2LOG2E : NLOG2E;
        int n = tgt * 64 + kcol;                   // gate row
        bias_s[j] = sc * (b_ih[n] + b_hh[n]);
        wih_s[j]  = sc * W_ih[n];
        #pragma unroll
        for (int kh = 0; kh < 2; ++kh) {
            const float* wr = W_hh + n * 64 + kh * 32 + quad * 8;
            bf16x8 hi, lo;
            #pragma unroll
            for (int jj = 0; jj < 8; ++jj) {
                float w = sc * wr[jj];
                short h16 = f2bf(w);
                hi[jj] = h16;
                lo[jj] = f2bf(w - bf2f(h16));
            }
            Bhi[j][kh] = hi;
            Blo[j][kh] = lo;
        }
    }

    float cc[2] = {0.f, 0.f};                 // this wave owns rows r = 2p, 2p+1
    const int aoff = l15 * HSTRIDE + quad * 8;
    const int row0 = 2 * p;                   // owned rows
    const int roww = 2 * (p ^ 1);             // rows written to partner

    __syncthreads();

    for (int t = 0; t < T_STEPS; ++t) {
        const int rb = t & 1, wb = rb ^ 1;

        // A fragments (hi/lo bf16 h), kh = 0 / +32; all 16B-aligned with HSTRIDE=72
        const short* hhi = &hbuf[rb][0][0][0];
        const short* hlo = &hbuf[rb][1][0][0];
        bf16x8 ahi0 = *reinterpret_cast<const bf16x8*>(hhi + aoff);
        bf16x8 ahi1 = *reinterpret_cast<const bf16x8*>(hhi + aoff + 32);
        bf16x8 alo0 = *reinterpret_cast<const bf16x8*>(hlo + aoff);
        bf16x8 alo1 = *reinterpret_cast<const bf16x8*>(hlo + aoff + 32);

        float xv[4];
        #pragma unroll
        for (int r = 0; r < 4; ++r) xv[r] = x_lds[(quad * 4 + r) * XSTRIDE + t];

        f32x4 acc0, acc1;
        #pragma unroll
        for (int r = 0; r < 4; ++r) {
            acc0[r] = bias_s[0] + wih_s[0] * xv[r];
            acc1[r] = bias_s[1] + wih_s[1] * xv[r];
        }
        // 3-pass split-bf16: Ahi*Bhi + Alo*Bhi + Ahi*Blo  (~fp32 precision)
        acc0 = __builtin_amdgcn_mfma_f32_16x16x32_bf16(ahi0, Bhi[0][0], acc0, 0, 0, 0);
        acc0 = __builtin_amdgcn_mfma_f32_16x16x32_bf16(ahi1, Bhi[0][1], acc0, 0, 0, 0);
        acc0 = __builtin_amdgcn_mfma_f32_16x16x32_bf16(alo0, Bhi[0][0], acc0, 0, 0, 0);
        acc0 = __builtin_amdgcn_mfma_f32_16x16x32_bf16(alo1, Bhi[0][1], acc0, 0, 0, 0);
        acc0 = __builtin_amdgcn_mfma_f32_16x16x32_bf16(ahi0, Blo[0][0], acc0, 0, 0, 0);
        acc0 = __builtin_amdgcn_mfma_f32_16x16x32_bf16(ahi1, Blo[0][1], acc0, 0, 0, 0);
        acc1 = __builtin_amdgcn_mfma_f32_16x16x32_bf16(ahi0, Bhi[1][0], acc1, 0, 0, 0);
        acc1 = __builtin_amdgcn_mfma_f32_16x16x32_bf16(ahi1, Bhi[1][1], acc1, 0, 0, 0);
        acc1 = __builtin_amdgcn_mfma_f32_16x16x32_bf16(alo0, Bhi[1][0], acc1, 0, 0, 0);
        acc1 = __builtin_amdgcn_mfma_f32_16x16x32_bf16(alo1, Bhi[1][1], acc1, 0, 0, 0);
        acc1 = __builtin_amdgcn_mfma_f32_16x16x32_bf16(ahi0, Blo[1][0], acc1, 0, 0, 0);
        acc1 = __builtin_amdgcn_mfma_f32_16x16x32_bf16(ahi1, Blo[1][1], acc1, 0, 0, 0);

        // activate own two gates for all 4 rows
        float gA[4], gB[4];
        if (p == 0) {
            #pragma unroll
            for (int r = 0; r < 4; ++r) {          // I, F
                gA[r] = RCPF(1.0f + EXP2F(acc0[r]));
                gB[r] = RCPF(1.0f + EXP2F(acc1[r]));
            }
        } else {
            #pragma unroll
            for (int r = 0; r < 4; ++r) {          // G (tanh), O (sig)
                gA[r] = 1.0f - 2.0f * RCPF(1.0f + EXP2F(acc0[r]));
                gB[r] = RCPF(1.0f + EXP2F(acc1[r]));
            }
        }
        // hand the partner its two rows
        #pragma unroll
        for (int j = 0; j < 2; ++j) {
            int r = roww + j;
            int b = quad * 4 + r;
            exch[b * E2S + kcol] = make_float2(gA[r], gB[r]);
        }
        __syncthreads();

        // cell update for owned rows; write h hi+lo
        #pragma unroll
        for (int j = 0; j < 2; ++j) {
            int r = row0 + j;
            int b = quad * 4 + r;
            float2 e = exch[b * E2S + kcol];
            float I, F, G, O;
            if (p == 0) { I = gA[r]; F = gB[r]; G = e.x; O = e.y; }
            else        { G = gA[r]; O = gB[r]; I = e.x; F = e.y; }
            float c = F * cc[j] + I * G;
            cc[j] = c;
            float th = 1.0f - 2.0f * RCPF(1.0f + EXP2F(c * P2LOG2E));  // tanh(c)
            float hv = O * th;
            short hh = f2bf(hv);
            short hl = f2bf(hv - bf2f(hh));
            hbuf[wb][0][b][kcol] = hh;
            hbuf[wb][1][b][kcol] = hl;
        }
        __syncthreads();
    }

    // ---- final FC: h final lives in hbuf[0] (t=511 wrote wb=0) ----
    if (tid < 16) {
        int b = tid;
        float ssum = b_fc[0];
        #pragma unroll 4
        for (int k = 0; k < 64; ++k)
            ssum += (bf2f(hbuf[0][0][b][k]) + bf2f(hbuf[0][1][b][k])) * W_fc[k];
        out[b0 + b] = ssum;
    }
}

extern "C" void kernel_launch(void* const* d_in, const int* in_sizes, int n_in,
                              void* d_out, int out_size, void* d_ws, size_t ws_size,
                              hipStream_t stream) {
    const float* x    = (const float*)d_in[0];
    const float* W_ih = (const float*)d_in[1];
    const float* W_hh = (const float*)d_in[2];
    const float* b_ih = (const float*)d_in[3];
    const float* b_hh = (const float*)d_in[4];
    const float* W_fc = (const float*)d_in[5];
    const float* b_fc = (const float*)d_in[6];
    float* out = (float*)d_out;
    const int B = in_sizes[0] / T_STEPS;   // 4096
    lstm_persist<<<dim3(B / BT), dim3(512), 0, stream>>>(
        x, W_ih, W_hh, b_ih, b_hh, W_fc, b_fc, out);
}